// Round 1
// baseline (371.928 us; speedup 1.0000x reference)
//
#include <hip/hip_runtime.h>
#include <math.h>

// Problem constants (from reference setup_inputs)
constexpr int N = 262144;   // rows
constexpr int D = 256;      // embedding dim
constexpr int C = 64;       // number of centers
constexpr float EPS_NORM  = 1e-8f;
constexpr float CLAMP_MIN = 1e-12f;
constexpr float CLAMP_MAX = 1e12f;

// Pre-kernel: one wave per center, compute ||center_c|| into d_ws.
__global__ __launch_bounds__(64) void center_norm_kernel(
        const float* __restrict__ centers, float* __restrict__ cnorm) {
    const int c = blockIdx.x;
    const int lane = threadIdx.x;          // 0..63
    float4 v = reinterpret_cast<const float4*>(centers + c * D)[lane];
    float s = v.x * v.x + v.y * v.y + v.z * v.z + v.w * v.w;
    #pragma unroll
    for (int off = 32; off >= 1; off >>= 1)
        s += __shfl_xor(s, off, 64);
    if (lane == 0) cnorm[c] = sqrtf(s);
}

// Main kernel: one wave per row (grid-stride). 64 lanes x float4 = 256 floats
// = one fully coalesced 1 KiB row read. Two 6-step butterfly reductions
// (dot, ||x||^2); center norm looked up from cnorm. One atomicAdd per block.
__global__ __launch_bounds__(256) void inner_cos_kernel(
        const float* __restrict__ emb,
        const int*   __restrict__ label,
        const float* __restrict__ centers,
        const float* __restrict__ cnorm,
        float* __restrict__ out) {
    const int lane  = threadIdx.x & 63;
    const int wave  = threadIdx.x >> 6;        // 0..3
    const int gwave = (blockIdx.x << 2) | wave;
    const int nwave = gridDim.x << 2;

    float lsum = 0.0f;
    for (int row = gwave; row < N; row += nwave) {
        const int lab = label[row];            // wave-uniform broadcast load
        const float4 x = reinterpret_cast<const float4*>(emb + (size_t)row * D)[lane];
        const float4 c = reinterpret_cast<const float4*>(centers + lab * D)[lane];

        float dot = x.x * c.x + x.y * c.y + x.z * c.z + x.w * c.w;
        float nx2 = x.x * x.x + x.y * x.y + x.z * x.z + x.w * x.w;

        #pragma unroll
        for (int off = 32; off >= 1; off >>= 1) {
            dot += __shfl_xor(dot, off, 64);
            nx2 += __shfl_xor(nx2, off, 64);
        }
        // all 64 lanes now hold the full-row dot and nx2
        const float denom = fmaxf(sqrtf(nx2) * cnorm[lab], EPS_NORM);
        float cd = 1.0f - dot / denom;
        cd = fminf(fmaxf(cd, CLAMP_MIN), CLAMP_MAX);
        lsum += cd;                            // identical across lanes
    }

    __shared__ float ssum[4];
    if (lane == 0) ssum[wave] = lsum;
    __syncthreads();
    if (threadIdx.x == 0) {
        const float s = (ssum[0] + ssum[1]) + (ssum[2] + ssum[3]);
        atomicAdd(out, s * (1.0f / (float)N));   // device-scope by default
    }
}

extern "C" void kernel_launch(void* const* d_in, const int* in_sizes, int n_in,
                              void* d_out, int out_size, void* d_ws, size_t ws_size,
                              hipStream_t stream) {
    const float* emb     = (const float*)d_in[0];
    const int*   label   = (const int*)d_in[1];
    const float* centers = (const float*)d_in[2];
    float* out   = (float*)d_out;
    float* cnorm = (float*)d_ws;               // 64 floats of scratch

    // d_out is re-poisoned to 0xAA before every timed launch — zero it.
    hipMemsetAsync(d_out, 0, sizeof(float), stream);

    center_norm_kernel<<<C, 64, 0, stream>>>(centers, cnorm);

    // 2048 blocks x 256 threads = 8192 waves = 32 waves/CU (max occupancy);
    // each wave streams 32 rows.
    inner_cos_kernel<<<2048, 256, 0, stream>>>(emb, label, centers, cnorm, out);
}

// Round 2
// 358.348 us; speedup vs baseline: 1.0379x; 1.0379x over previous
//
#include <hip/hip_runtime.h>
#include <math.h>

// Problem constants (from reference setup_inputs)
constexpr int N = 262144;   // rows
constexpr int D = 256;      // embedding dim
constexpr int C = 64;       // number of centers
constexpr float EPS_NORM  = 1e-8f;
constexpr float CLAMP_MIN = 1e-12f;
constexpr float CLAMP_MAX = 1e12f;

constexpr int BLOCKS = 2048;   // 8 blocks/CU co-resident, 32 waves/CU

// Pre-kernel: one wave per center, compute ||center_c|| into ws[0..63].
__global__ __launch_bounds__(64) void center_norm_kernel(
        const float* __restrict__ centers, float* __restrict__ cnorm) {
    const int c = blockIdx.x;
    const int lane = threadIdx.x;          // 0..63
    float4 v = reinterpret_cast<const float4*>(centers + c * D)[lane];
    float s = v.x * v.x + v.y * v.y + v.z * v.z + v.w * v.w;
    #pragma unroll
    for (int off = 32; off >= 1; off >>= 1)
        s += __shfl_xor(s, off, 64);
    if (lane == 0) cnorm[c] = sqrtf(s);
}

// Main kernel: 16 lanes per row, 4 rows per wave-iteration.
// Pass j: each 16-lane group reads 256 B contiguous of its row (float4/lane)
// -> 1 KiB per wave instruction, fully coalesced. Reduction over 16 lanes:
// 4 butterfly steps x 2 values = 8 ds ops per 4 rows (vs 12 per row before),
// and the 8 chains are independent -> latency overlaps.
// Block partial sums go to ws (no global atomics).
__global__ __launch_bounds__(256) void inner_cos_kernel(
        const float* __restrict__ emb,
        const int*   __restrict__ label,
        const float* __restrict__ centers,
        const float* __restrict__ cnorm,
        float* __restrict__ partials) {
    const int lane = threadIdx.x & 63;
    const int wave = threadIdx.x >> 6;     // 0..3
    const int sub  = lane & 15;            // lane within 16-group
    const int quad = lane >> 4;            // which of the 4 rows
    const int gwave   = (blockIdx.x << 2) | wave;
    const int ngroups = N >> 2;            // 65536 groups of 4 rows
    const int nwave   = BLOCKS << 2;       // 8192 waves -> 8 groups/wave

    float lsum = 0.0f;
    for (int g = gwave; g < ngroups; g += nwave) {
        const int row = (g << 2) | quad;
        const int lab = label[row];                    // 16 B segment / wave
        const float4* xrow = reinterpret_cast<const float4*>(emb + (size_t)row * D);
        const float4* crow = reinterpret_cast<const float4*>(centers + (size_t)lab * D);

        float dot = 0.0f, nx2 = 0.0f;
        #pragma unroll
        for (int j = 0; j < 4; ++j) {
            const float4 x = xrow[(j << 4) + sub];
            const float4 c = crow[(j << 4) + sub];
            dot = fmaf(x.x, c.x, dot); dot = fmaf(x.y, c.y, dot);
            dot = fmaf(x.z, c.z, dot); dot = fmaf(x.w, c.w, dot);
            nx2 = fmaf(x.x, x.x, nx2); nx2 = fmaf(x.y, x.y, nx2);
            nx2 = fmaf(x.z, x.z, nx2); nx2 = fmaf(x.w, x.w, nx2);
        }
        // reduce across the 16-lane group (masks stay within the group)
        #pragma unroll
        for (int off = 8; off >= 1; off >>= 1) {
            dot += __shfl_xor(dot, off, 64);
            nx2 += __shfl_xor(nx2, off, 64);
        }
        const float denom = fmaxf(sqrtf(nx2) * cnorm[lab], EPS_NORM);
        float cd = 1.0f - dot / denom;
        cd = fminf(fmaxf(cd, CLAMP_MIN), CLAMP_MAX);
        lsum += cd;    // identical across the 16 lanes of this group
    }

    // combine the 4 quads: masks 16,32 sum one representative of each quad
    lsum += __shfl_xor(lsum, 16, 64);
    lsum += __shfl_xor(lsum, 32, 64);
    // every lane now holds the wave's exact row-sum (each row counted once)

    __shared__ float ssum[4];
    if (lane == 0) ssum[wave] = lsum;
    __syncthreads();
    if (threadIdx.x == 0)
        partials[blockIdx.x] = (ssum[0] + ssum[1]) + (ssum[2] + ssum[3]);
}

// Final reduction: 2048 partials -> scalar mean.
__global__ __launch_bounds__(256) void finalize_kernel(
        const float* __restrict__ partials, float* __restrict__ out) {
    float s = 0.0f;
    #pragma unroll
    for (int i = 0; i < BLOCKS / 256; ++i)
        s += partials[threadIdx.x + (i << 8)];
    #pragma unroll
    for (int off = 32; off >= 1; off >>= 1)
        s += __shfl_xor(s, off, 64);
    __shared__ float ss[4];
    if ((threadIdx.x & 63) == 0) ss[threadIdx.x >> 6] = s;
    __syncthreads();
    if (threadIdx.x == 0)
        out[0] = ((ss[0] + ss[1]) + (ss[2] + ss[3])) * (1.0f / (float)N);
}

extern "C" void kernel_launch(void* const* d_in, const int* in_sizes, int n_in,
                              void* d_out, int out_size, void* d_ws, size_t ws_size,
                              hipStream_t stream) {
    const float* emb     = (const float*)d_in[0];
    const int*   label   = (const int*)d_in[1];
    const float* centers = (const float*)d_in[2];
    float* out      = (float*)d_out;
    float* cnorm    = (float*)d_ws;                 // 64 floats
    float* partials = (float*)d_ws + 64;            // 2048 floats

    center_norm_kernel<<<C, 64, 0, stream>>>(centers, cnorm);
    inner_cos_kernel<<<BLOCKS, 256, 0, stream>>>(emb, label, centers, cnorm, partials);
    finalize_kernel<<<1, 256, 0, stream>>>(partials, out);
}

// Round 3
// 357.443 us; speedup vs baseline: 1.0405x; 1.0025x over previous
//
#include <hip/hip_runtime.h>
#include <math.h>

// Problem constants (from reference setup_inputs)
constexpr int N = 262144;   // rows
constexpr int D = 256;      // embedding dim
constexpr int C = 64;       // number of centers
constexpr float CLAMP_MIN = 1e-12f;
constexpr float CLAMP_MAX = 1e12f;

constexpr int BLOCKS = 2048;        // 8 blocks/CU
constexpr int NWAVES = BLOCKS * 4;  // 8192 waves
constexpr int GPW    = (N / 4) / NWAVES;  // 8 groups (of 4 rows) per wave

// Pre-kernel: one wave per center; write normalized center c/||c|| into ws.
__global__ __launch_bounds__(64) void center_normalize_kernel(
        const float* __restrict__ centers, float* __restrict__ cn) {
    const int c = blockIdx.x;
    const int lane = threadIdx.x;          // 0..63
    float4 v = reinterpret_cast<const float4*>(centers + c * D)[lane];
    float s = v.x * v.x + v.y * v.y + v.z * v.z + v.w * v.w;
    #pragma unroll
    for (int off = 32; off >= 1; off >>= 1)
        s += __shfl_xor(s, off, 64);
    const float inv = rsqrtf(fmaxf(s, 1e-24f));
    float4 o = make_float4(v.x * inv, v.y * inv, v.z * inv, v.w * inv);
    reinterpret_cast<float4*>(cn + c * D)[lane] = o;
}

// Main kernel: 16 lanes per row, 4 rows per group, 8 groups per wave
// (compile-time). Labels for all 32 rows prefetched in ONE gather before the
// loop (per-iteration label = shfl, no dependent load). Depth-2 software
// pipeline: group k+1's 8 loads issue before group k's compute, so memory
// latency hides under compute + other waves.
__global__ __launch_bounds__(256) void inner_cos_kernel(
        const float* __restrict__ emb,
        const int*   __restrict__ label,
        const float* __restrict__ cnormed,
        float* __restrict__ partials) {
    const int lane = threadIdx.x & 63;
    const int wave = threadIdx.x >> 6;     // 0..3
    const int sub  = lane & 15;            // lane within 16-group
    const int quad = lane >> 4;            // which of the 4 rows in the group
    const int gwave = (blockIdx.x << 2) | wave;   // 0..8191

    // Prefetch all 32 labels this wave will need:
    // lane (k*4+q) holds label of row 4*gwave + k*4*NWAVES + q, k=0..7.
    int mylab = 0;
    if (lane < 32) {
        const int k = lane >> 2, q = lane & 3;
        mylab = label[4 * gwave + k * (4 * NWAVES) + q];
    }

    const float4* xbase = reinterpret_cast<const float4*>(emb);
    const float4* cbase = reinterpret_cast<const float4*>(cnormed);

    float lsum = 0.0f;
    float4 x[4], c[4];

    // prologue: load group 0
    {
        const int lab  = __shfl(mylab, quad);         // k=0
        const int row0 = 4 * gwave + quad;
        const float4* xr = xbase + (size_t)row0 * (D / 4);
        const float4* cr = cbase + (size_t)lab  * (D / 4);
        #pragma unroll
        for (int j = 0; j < 4; ++j) { x[j] = xr[(j << 4) + sub]; c[j] = cr[(j << 4) + sub]; }
    }

    #pragma unroll
    for (int k = 0; k < GPW; ++k) {
        float4 xn[4], cn[4];
        if (k + 1 < GPW) {   // issue next group's loads before current compute
            const int labn = __shfl(mylab, ((k + 1) << 2) + quad);
            const int rown = 4 * gwave + (k + 1) * (4 * NWAVES) + quad;
            const float4* xr = xbase + (size_t)rown * (D / 4);
            const float4* cr = cbase + (size_t)labn * (D / 4);
            #pragma unroll
            for (int j = 0; j < 4; ++j) { xn[j] = xr[(j << 4) + sub]; cn[j] = cr[(j << 4) + sub]; }
        }

        float dot = 0.0f, nx2 = 0.0f;
        #pragma unroll
        for (int j = 0; j < 4; ++j) {
            dot = fmaf(x[j].x, c[j].x, dot); dot = fmaf(x[j].y, c[j].y, dot);
            dot = fmaf(x[j].z, c[j].z, dot); dot = fmaf(x[j].w, c[j].w, dot);
            nx2 = fmaf(x[j].x, x[j].x, nx2); nx2 = fmaf(x[j].y, x[j].y, nx2);
            nx2 = fmaf(x[j].z, x[j].z, nx2); nx2 = fmaf(x[j].w, x[j].w, nx2);
        }
        #pragma unroll
        for (int off = 8; off >= 1; off >>= 1) {
            dot += __shfl_xor(dot, off, 64);
            nx2 += __shfl_xor(nx2, off, 64);
        }
        // centers pre-normalized: cos = dot * rsqrt(||x||^2)
        float cd = 1.0f - dot * rsqrtf(fmaxf(nx2, 1e-24f));
        cd = fminf(fmaxf(cd, CLAMP_MIN), CLAMP_MAX);
        lsum += cd;          // identical across the 16 lanes of this group

        if (k + 1 < GPW) {
            #pragma unroll
            for (int j = 0; j < 4; ++j) { x[j] = xn[j]; c[j] = cn[j]; }
        }
    }

    // combine the 4 quads (each row counted once per 16-lane group)
    lsum += __shfl_xor(lsum, 16, 64);
    lsum += __shfl_xor(lsum, 32, 64);

    __shared__ float ssum[4];
    if (lane == 0) ssum[wave] = lsum;
    __syncthreads();
    if (threadIdx.x == 0)
        partials[blockIdx.x] = (ssum[0] + ssum[1]) + (ssum[2] + ssum[3]);
}

// Final reduction: 2048 partials -> scalar mean.
__global__ __launch_bounds__(256) void finalize_kernel(
        const float* __restrict__ partials, float* __restrict__ out) {
    float s = 0.0f;
    #pragma unroll
    for (int i = 0; i < BLOCKS / 256; ++i)
        s += partials[threadIdx.x + (i << 8)];
    #pragma unroll
    for (int off = 32; off >= 1; off >>= 1)
        s += __shfl_xor(s, off, 64);
    __shared__ float ss[4];
    if ((threadIdx.x & 63) == 0) ss[threadIdx.x >> 6] = s;
    __syncthreads();
    if (threadIdx.x == 0)
        out[0] = ((ss[0] + ss[1]) + (ss[2] + ss[3])) * (1.0f / (float)N);
}

extern "C" void kernel_launch(void* const* d_in, const int* in_sizes, int n_in,
                              void* d_out, int out_size, void* d_ws, size_t ws_size,
                              hipStream_t stream) {
    const float* emb     = (const float*)d_in[0];
    const int*   label   = (const int*)d_in[1];
    const float* centers = (const float*)d_in[2];
    float* out      = (float*)d_out;
    float* cnormed  = (float*)d_ws;                  // 64*256 floats = 64 KiB
    float* partials = (float*)d_ws + C * D;          // 2048 floats

    center_normalize_kernel<<<C, 64, 0, stream>>>(centers, cnormed);
    inner_cos_kernel<<<BLOCKS, 256, 0, stream>>>(emb, label, cnormed, partials);
    finalize_kernel<<<1, 256, 0, stream>>>(partials, out);
}

// Round 5
// 334.780 us; speedup vs baseline: 1.1110x; 1.0677x over previous
//
#include <hip/hip_runtime.h>
#include <math.h>

// Problem constants (from reference setup_inputs)
constexpr int N = 262144;   // rows
constexpr int D = 256;      // embedding dim
constexpr int C = 64;       // number of centers
constexpr float CLAMP_MIN = 1e-12f;
constexpr float CLAMP_MAX = 1e12f;

constexpr int BLOCKS  = 512;          // 1024-thread blocks
constexpr int WPB     = 16;           // waves per block
constexpr int NWAVES  = BLOCKS * WPB; // 8192 waves
constexpr int GPW     = (N / 4) / NWAVES;  // 8 groups (of 4 rows) per wave

// native clang vector type: __builtin_nontemporal_load requires it
typedef float fvec4 __attribute__((ext_vector_type(4)));

// Pre-kernel: one wave per center; write normalized center c/||c|| into ws.
__global__ __launch_bounds__(64) void center_normalize_kernel(
        const float* __restrict__ centers, float* __restrict__ cn) {
    const int c = blockIdx.x;
    const int lane = threadIdx.x;          // 0..63
    float4 v = reinterpret_cast<const float4*>(centers + c * D)[lane];
    float s = v.x * v.x + v.y * v.y + v.z * v.z + v.w * v.w;
    #pragma unroll
    for (int off = 32; off >= 1; off >>= 1)
        s += __shfl_xor(s, off, 64);
    const float inv = rsqrtf(fmaxf(s, 1e-24f));
    float4 o = make_float4(v.x * inv, v.y * inv, v.z * inv, v.w * inv);
    reinterpret_cast<float4*>(cn + c * D)[lane] = o;
}

// Main kernel: 16 lanes per row, 4 rows per group, 8 groups per wave.
// The 64 KiB normalized-center table lives in LDS (loaded once per block),
// so the ONLY VMEM traffic in the loop is the nontemporal emb stream
// (4 x dwordx4 per wave per group) + one label gather per wave.
__global__ __launch_bounds__(1024) void inner_cos_kernel(
        const float* __restrict__ emb,
        const int*   __restrict__ label,
        const float* __restrict__ cnormed,
        float* __restrict__ partials) {
    __shared__ float4 ctab[C * D / 4];     // 64 KiB
    __shared__ float  ssum[WPB];

    // cooperative table load: 1024 threads x 4 float4
    {
        const float4* src = reinterpret_cast<const float4*>(cnormed);
        #pragma unroll
        for (int i = 0; i < (C * D / 4) / 1024; ++i)
            ctab[threadIdx.x + i * 1024] = src[threadIdx.x + i * 1024];
    }

    const int lane = threadIdx.x & 63;
    const int wave = threadIdx.x >> 6;     // 0..15
    const int sub  = lane & 15;            // lane within 16-group
    const int quad = lane >> 4;            // which of the 4 rows in the group
    const int gwave = blockIdx.x * WPB + wave;    // 0..8191

    // Prefetch all 32 labels this wave needs:
    // lane (k*4+q) holds label of row 4*gwave + k*4*NWAVES + q, k=0..7.
    int mylab = 0;
    if (lane < 32) {
        const int k = lane >> 2, q = lane & 3;
        mylab = label[4 * gwave + k * (4 * NWAVES) + q];
    }

    __syncthreads();                       // table ready

    const fvec4* xbase = reinterpret_cast<const fvec4*>(emb);

    float lsum = 0.0f;
    fvec4 x[4];

    // prologue: stream group 0's x (nontemporal: no L2 churn)
    {
        const fvec4* xr = xbase + (size_t)(4 * gwave + quad) * (D / 4);
        #pragma unroll
        for (int j = 0; j < 4; ++j)
            x[j] = __builtin_nontemporal_load(xr + (j << 4) + sub);
    }

    #pragma unroll
    for (int k = 0; k < GPW; ++k) {
        fvec4 xn[4];
        if (k + 1 < GPW) {   // issue next group's x-loads before current compute
            const int rown = 4 * gwave + (k + 1) * (4 * NWAVES) + quad;
            const fvec4* xr = xbase + (size_t)rown * (D / 4);
            #pragma unroll
            for (int j = 0; j < 4; ++j)
                xn[j] = __builtin_nontemporal_load(xr + (j << 4) + sub);
        }

        // c from LDS: 4 x ds_read_b128, conflict-free per 16-lane phase
        const int lab = __shfl(mylab, (k << 2) + quad);
        const float4* crow = ctab + lab * (D / 4);
        float4 c0 = crow[sub +  0], c1 = crow[sub + 16];
        float4 c2 = crow[sub + 32], c3 = crow[sub + 48];

        float dot = 0.0f, nx2 = 0.0f;
        dot = fmaf(x[0].x, c0.x, dot); dot = fmaf(x[0].y, c0.y, dot);
        dot = fmaf(x[0].z, c0.z, dot); dot = fmaf(x[0].w, c0.w, dot);
        dot = fmaf(x[1].x, c1.x, dot); dot = fmaf(x[1].y, c1.y, dot);
        dot = fmaf(x[1].z, c1.z, dot); dot = fmaf(x[1].w, c1.w, dot);
        dot = fmaf(x[2].x, c2.x, dot); dot = fmaf(x[2].y, c2.y, dot);
        dot = fmaf(x[2].z, c2.z, dot); dot = fmaf(x[2].w, c2.w, dot);
        dot = fmaf(x[3].x, c3.x, dot); dot = fmaf(x[3].y, c3.y, dot);
        dot = fmaf(x[3].z, c3.z, dot); dot = fmaf(x[3].w, c3.w, dot);
        #pragma unroll
        for (int j = 0; j < 4; ++j) {
            nx2 = fmaf(x[j].x, x[j].x, nx2); nx2 = fmaf(x[j].y, x[j].y, nx2);
            nx2 = fmaf(x[j].z, x[j].z, nx2); nx2 = fmaf(x[j].w, x[j].w, nx2);
        }
        #pragma unroll
        for (int off = 8; off >= 1; off >>= 1) {
            dot += __shfl_xor(dot, off, 64);
            nx2 += __shfl_xor(nx2, off, 64);
        }
        // centers pre-normalized: cos = dot * rsqrt(||x||^2)
        float cd = 1.0f - dot * rsqrtf(fmaxf(nx2, 1e-24f));
        cd = fminf(fmaxf(cd, CLAMP_MIN), CLAMP_MAX);
        lsum += cd;          // identical across the 16 lanes of this group

        if (k + 1 < GPW) {
            #pragma unroll
            for (int j = 0; j < 4; ++j) x[j] = xn[j];
        }
    }

    // combine the 4 quads (each row counted once per 16-lane group)
    lsum += __shfl_xor(lsum, 16, 64);
    lsum += __shfl_xor(lsum, 32, 64);

    if (lane == 0) ssum[wave] = lsum;
    __syncthreads();
    if (threadIdx.x == 0) {
        float s = 0.0f;
        #pragma unroll
        for (int w = 0; w < WPB; ++w) s += ssum[w];
        partials[blockIdx.x] = s;
    }
}

// Final reduction: 512 partials -> scalar mean.
__global__ __launch_bounds__(256) void finalize_kernel(
        const float* __restrict__ partials, float* __restrict__ out) {
    float s = 0.0f;
    #pragma unroll
    for (int i = 0; i < BLOCKS / 256; ++i)
        s += partials[threadIdx.x + (i << 8)];
    #pragma unroll
    for (int off = 32; off >= 1; off >>= 1)
        s += __shfl_xor(s, off, 64);
    __shared__ float ss[4];
    if ((threadIdx.x & 63) == 0) ss[threadIdx.x >> 6] = s;
    __syncthreads();
    if (threadIdx.x == 0)
        out[0] = ((ss[0] + ss[1]) + (ss[2] + ss[3])) * (1.0f / (float)N);
}

extern "C" void kernel_launch(void* const* d_in, const int* in_sizes, int n_in,
                              void* d_out, int out_size, void* d_ws, size_t ws_size,
                              hipStream_t stream) {
    const float* emb     = (const float*)d_in[0];
    const int*   label   = (const int*)d_in[1];
    const float* centers = (const float*)d_in[2];
    float* out      = (float*)d_out;
    float* cnormed  = (float*)d_ws;                  // 64*256 floats = 64 KiB
    float* partials = (float*)d_ws + C * D;          // 512 floats

    center_normalize_kernel<<<C, 64, 0, stream>>>(centers, cnormed);
    inner_cos_kernel<<<BLOCKS, 1024, 0, stream>>>(emb, label, cnormed, partials);
    finalize_kernel<<<1, 256, 0, stream>>>(partials, out);
}